// Round 5
// baseline (95.487 us; speedup 1.0000x reference)
//
#include <hip/hip_runtime.h>

// sites [4096,128] f32, consensus [512,128] f32
// out = softmax(-L1dist, axis=-1) -> [4096,512] f32
#define N_SITES 4096
#define M_CONS  512
#define DIM     128

// Single dispatch, "last block finishes the stripe" fusion.
// Grid 512 blocks x 256 threads, 2 blocks/CU (64 KB LDS each).
//   rowBlk = bid & 63  (64 site rows), colBlk = bid >> 6 (64 cons cols)
//   -> all 8 col-chunks of a stripe share bid%8, i.e. the same XCD/L2.
// Dist phase (R4 core, proven): split-k x4 across waves, lane tile 8x8,
//   quad-XOR-swizzled LDS staging + conflict-free combine; stores POSITIVE
//   L1 distance to out (coalesced float4).
// Finish phase: per-stripe atomic counter in d_ws (zeroed per launch via
//   hipMemsetAsync); the 8th finisher block acquires and computes the row
//   softmax exp(min-d)/sum for its 64 rows in-place, reading hot L2 data.
__global__ __launch_bounds__(256, 2) void fused_dist_softmax(const float* __restrict__ sites,
                                                             const float* __restrict__ cons,
                                                             float* __restrict__ out,
                                                             unsigned int* __restrict__ ctr) {
    __shared__ __align__(16) float lds[16384];   // 64 KB
    float* s_sites = lds;                        // [64][128]
    float* s_cons  = lds + 8192;                 // [64][128]

    const int tid    = threadIdx.x;
    const int bid    = blockIdx.x;
    const int rowBlk = bid & 63;                 // stripe id; bid%8 == rowBlk%8 -> same XCD per stripe
    const int colBlk = bid >> 6;                 // 0..7

    // ---- stage sites tile (32 KB): quad stored at q ^ (r&7)
    {
        const float* g = sites + (size_t)rowBlk * 64 * DIM;
#pragma unroll
        for (int it = 0; it < 8; it++) {
            int f = tid + it * 256;              // 0..2047
            int r = f >> 5, q = f & 31;
            float4 v = *(const float4*)(g + r * DIM + (q << 2));
            *(float4*)&s_sites[r * DIM + ((q ^ (r & 7)) << 2)] = v;
        }
    }
    // ---- stage cons tile (32 KB): quad stored at q ^ ((r>>3)&7)
    {
        const float* g = cons + (size_t)colBlk * 64 * DIM;
#pragma unroll
        for (int it = 0; it < 8; it++) {
            int f = tid + it * 256;              // 0..2047
            int r = f >> 5, q = f & 31;
            float4 v = *(const float4*)(g + r * DIM + (q << 2));
            *(float4*)&s_cons[r * DIM + ((q ^ ((r >> 3) & 7)) << 2)] = v;
        }
    }

    const int kg   = tid >> 6;                   // wave = k-group, dims [kg*32,..+32)
    const int lane = tid & 63;
    const int lr   = lane >> 3;                  // 0..7
    const int lc   = lane & 7;                   // 0..7

    float acc[8][8];
#pragma unroll
    for (int i = 0; i < 8; i++)
#pragma unroll
        for (int j = 0; j < 8; j++) acc[i][j] = 0.f;

    __syncthreads();

    // ---- compute this k-group's 8 k-quads (cv held, sv streamed)
    const int q0 = kg << 3;
    for (int qq = 0; qq < 8; qq++) {
        const int q = q0 + qq;
        float4 cv[8];
        const int qs_c = (q ^ lc) << 2;          // cons rows of this lane: (r>>3)==lc
#pragma unroll
        for (int j = 0; j < 8; j++)
            cv[j] = *(const float4*)&s_cons[(lc * 8 + j) * DIM + qs_c];
        const int qs_s = (q ^ lr) << 2;          // site rows of this lane: (r&7)==lr
#pragma unroll
        for (int i = 0; i < 8; i++) {
            float4 sv = *(const float4*)&s_sites[(8 * i + lr) * DIM + qs_s];
#pragma unroll
            for (int j = 0; j < 8; j++) {
                acc[i][j] += fabsf(sv.x - cv[j].x);
                acc[i][j] += fabsf(sv.y - cv[j].y);
                acc[i][j] += fabsf(sv.z - cv[j].z);
                acc[i][j] += fabsf(sv.w - cv[j].w);
            }
        }
    }

    __syncthreads();                             // staging space now free

    // ---- dump partials: [kg][64 rows][16 quads], quad ^ (r&7)
    {
        float* base = lds + kg * 4096;
#pragma unroll
        for (int i = 0; i < 8; i++) {
            int r = 8 * i + lr;
            float4 v0 = { acc[i][0], acc[i][1], acc[i][2], acc[i][3] };
            float4 v1 = { acc[i][4], acc[i][5], acc[i][6], acc[i][7] };
            *(float4*)&base[r * 64 + (((lc * 2 + 0) ^ (r & 7)) << 2)] = v0;
            *(float4*)&base[r * 64 + (((lc * 2 + 1) ^ (r & 7)) << 2)] = v1;
        }
    }
    __syncthreads();

    // ---- sum 4 partials, coalesced float4 store of POSITIVE dist
    const int grow0 = rowBlk * 64;
    const int gcol0 = colBlk * 64;
#pragma unroll
    for (int oo = 0; oo < 4; oo++) {
        int o  = tid + oo * 256;                 // 0..1023 = 64 rows x 16 quads
        int r  = o >> 4;
        int qd = o & 15;
        const float* b0 = lds + r * 64 + ((qd ^ (r & 7)) << 2);
        float4 a = *(const float4*)(b0);
        float4 b = *(const float4*)(b0 + 4096);
        float4 c = *(const float4*)(b0 + 8192);
        float4 d = *(const float4*)(b0 + 12288);
        float4 s = { (a.x + b.x) + (c.x + d.x),
                     (a.y + b.y) + (c.y + d.y),
                     (a.z + b.z) + (c.z + d.z),
                     (a.w + b.w) + (c.w + d.w) };
        *(float4*)&out[(size_t)(grow0 + r) * M_CONS + gcol0 + (qd << 2)] = s;
    }

    // ---- stripe rendezvous: last of the 8 col-blocks does the softmax
    __threadfence();                             // release our stores device-wide
    __syncthreads();
    if (tid == 0) {
        unsigned int old = __hip_atomic_fetch_add(&ctr[rowBlk], 1u,
                                                  __ATOMIC_ACQ_REL, __HIP_MEMORY_SCOPE_AGENT);
        ((unsigned int*)lds)[0] = old;           // broadcast arrival index
    }
    __syncthreads();
    if (((unsigned int*)lds)[0] != 7u) return;   // not the finisher
    __threadfence();                             // acquire: see the other 7 blocks' stores

    // ---- softmax for rows [rowBlk*64, rowBlk*64+64): wave per row, 16 passes
    const int wave = tid >> 6;
#pragma unroll 4
    for (int rr = 0; rr < 16; rr++) {
        int row = grow0 + rr * 4 + wave;
        float* p = out + (size_t)row * M_CONS + lane * 8;
        float4 v0 = *(const float4*)p;
        float4 v1 = *(const float4*)(p + 4);
        float mn = fminf(fminf(fminf(v0.x, v0.y), fminf(v0.z, v0.w)),
                         fminf(fminf(v1.x, v1.y), fminf(v1.z, v1.w)));
#pragma unroll
        for (int off = 32; off > 0; off >>= 1) mn = fminf(mn, __shfl_xor(mn, off));
        float e[8];
        e[0] = __expf(mn - v0.x); e[1] = __expf(mn - v0.y);
        e[2] = __expf(mn - v0.z); e[3] = __expf(mn - v0.w);
        e[4] = __expf(mn - v1.x); e[5] = __expf(mn - v1.y);
        e[6] = __expf(mn - v1.z); e[7] = __expf(mn - v1.w);
        float s = ((e[0] + e[1]) + (e[2] + e[3])) + ((e[4] + e[5]) + (e[6] + e[7]));
#pragma unroll
        for (int off = 32; off > 0; off >>= 1) s += __shfl_xor(s, off);
        const float inv = 1.f / s;
        float4 o0 = { e[0] * inv, e[1] * inv, e[2] * inv, e[3] * inv };
        float4 o1 = { e[4] * inv, e[5] * inv, e[6] * inv, e[7] * inv };
        *(float4*)p       = o0;
        *(float4*)(p + 4) = o1;
    }
}

extern "C" void kernel_launch(void* const* d_in, const int* in_sizes, int n_in,
                              void* d_out, int out_size, void* d_ws, size_t ws_size,
                              hipStream_t stream) {
    const float* sites = (const float*)d_in[0];
    const float* cons  = (const float*)d_in[1];
    float* out = (float*)d_out;
    unsigned int* ctr = (unsigned int*)d_ws;

    hipMemsetAsync(ctr, 0, 64 * sizeof(unsigned int), stream);  // stripe counters = 0
    fused_dist_softmax<<<512, 256, 0, stream>>>(sites, cons, out, ctr);
}

// Round 6
// 58.146 us; speedup vs baseline: 1.6422x; 1.6422x over previous
//
#include <hip/hip_runtime.h>

// sites [4096,128] f32, consensus [512,128] f32
// out = softmax(-L1dist, axis=-1) -> [4096,512] f32
#define N_SITES 4096
#define M_CONS  512
#define DIM     128

// K1: negated L1 distance. Grid 64x8 = 512 blocks (2/CU), 256 threads.
// Block tile 64 rows x 64 cols, split-k x4 (wave kg covers k [kg*32,kg*32+32)).
// Lane: 8 rows (8i+lr) x 8 consecutive cols (lc*8+j), acc[8][8].
// LDS 64 KB: sites[64][128] quad-swizzled by (r&7), cons[64][128] by ((r>>3)&7).
// Inner loop: SOURCE-LEVEL DOUBLE-BUFFERED quad pipeline - all 16 ds_read_b128
// of quad q+1 are issued before the 512-VALU compute of quad q consumes its
// buffer. Fully unrolled so cv[2][8]/sv[2][8] indices are compile-time (no
// scratch). Live set ~200 VGPR; __launch_bounds__(256,2) budget = 256.
// Combine: reuse staging LDS as [kg][64 rows][16 quads ^ (r&7)]; all 256
// threads sum 4 partials, negate, coalesced float4 store.
__global__ __launch_bounds__(256, 2) void dist_kernel(const float* __restrict__ sites,
                                                      const float* __restrict__ cons,
                                                      float* __restrict__ out) {
    __shared__ __align__(16) float lds[16384];   // 64 KB
    float* s_sites = lds;                        // [64][128]
    float* s_cons  = lds + 8192;                 // [64][128]

    const int tid    = threadIdx.x;
    const int rowBlk = blockIdx.x;               // 0..63
    const int colBlk = blockIdx.y;               // 0..7

    // ---- stage sites tile (32 KB): quad stored at q ^ (r&7)
    {
        const float* g = sites + (size_t)rowBlk * 64 * DIM;
#pragma unroll
        for (int it = 0; it < 8; it++) {
            int f = tid + it * 256;              // 0..2047
            int r = f >> 5, q = f & 31;
            float4 v = *(const float4*)(g + r * DIM + (q << 2));
            *(float4*)&s_sites[r * DIM + ((q ^ (r & 7)) << 2)] = v;
        }
    }
    // ---- stage cons tile (32 KB): quad stored at q ^ ((r>>3)&7)
    {
        const float* g = cons + (size_t)colBlk * 64 * DIM;
#pragma unroll
        for (int it = 0; it < 8; it++) {
            int f = tid + it * 256;              // 0..2047
            int r = f >> 5, q = f & 31;
            float4 v = *(const float4*)(g + r * DIM + (q << 2));
            *(float4*)&s_cons[r * DIM + ((q ^ ((r >> 3) & 7)) << 2)] = v;
        }
    }

    const int kg   = tid >> 6;                   // wave = k-group
    const int lane = tid & 63;
    const int lr   = lane >> 3;                  // 0..7
    const int lc   = lane & 7;                   // 0..7

    float acc[8][8];
#pragma unroll
    for (int i = 0; i < 8; i++)
#pragma unroll
        for (int j = 0; j < 8; j++) acc[i][j] = 0.f;

    __syncthreads();

    // ---- compute: 8 k-quads, double-buffered in registers
    const int q0 = kg << 3;
    float4 cv[2][8], sv[2][8];

    // prologue: load quad q0 into buffer 0
    {
        const int qs_c = (q0 ^ lc) << 2;
        const int qs_s = (q0 ^ lr) << 2;
#pragma unroll
        for (int j = 0; j < 8; j++)
            cv[0][j] = *(const float4*)&s_cons[(lc * 8 + j) * DIM + qs_c];
#pragma unroll
        for (int i = 0; i < 8; i++)
            sv[0][i] = *(const float4*)&s_sites[(8 * i + lr) * DIM + qs_s];
    }

#pragma unroll
    for (int qq = 0; qq < 8; qq++) {
        const int cur = qq & 1;
        const int nxt = cur ^ 1;
        if (qq < 7) {                            // issue next quad's 16 loads first
            const int qn   = q0 + qq + 1;
            const int qs_c = (qn ^ lc) << 2;
            const int qs_s = (qn ^ lr) << 2;
#pragma unroll
            for (int j = 0; j < 8; j++)
                cv[nxt][j] = *(const float4*)&s_cons[(lc * 8 + j) * DIM + qs_c];
#pragma unroll
            for (int i = 0; i < 8; i++)
                sv[nxt][i] = *(const float4*)&s_sites[(8 * i + lr) * DIM + qs_s];
        }
#pragma unroll
        for (int i = 0; i < 8; i++) {
#pragma unroll
            for (int j = 0; j < 8; j++) {
                acc[i][j] += fabsf(sv[cur][i].x - cv[cur][j].x);
                acc[i][j] += fabsf(sv[cur][i].y - cv[cur][j].y);
                acc[i][j] += fabsf(sv[cur][i].z - cv[cur][j].z);
                acc[i][j] += fabsf(sv[cur][i].w - cv[cur][j].w);
            }
        }
    }

    __syncthreads();                             // staging space now free

    // ---- dump partials: [kg][64 rows][16 quads], quad ^ (r&7)
    {
        float* base = lds + kg * 4096;
#pragma unroll
        for (int i = 0; i < 8; i++) {
            int r = 8 * i + lr;
            float4 v0 = { acc[i][0], acc[i][1], acc[i][2], acc[i][3] };
            float4 v1 = { acc[i][4], acc[i][5], acc[i][6], acc[i][7] };
            *(float4*)&base[r * 64 + (((lc * 2 + 0) ^ (r & 7)) << 2)] = v0;
            *(float4*)&base[r * 64 + (((lc * 2 + 1) ^ (r & 7)) << 2)] = v1;
        }
    }
    __syncthreads();

    // ---- all 256 threads: sum 4 partials, negate, coalesced float4 store
    const int grow0 = rowBlk * 64;
    const int gcol0 = colBlk * 64;
#pragma unroll
    for (int oo = 0; oo < 4; oo++) {
        int o  = tid + oo * 256;                 // 0..1023 = 64 rows x 16 quads
        int r  = o >> 4;
        int qd = o & 15;
        const float* b0 = lds + r * 64 + ((qd ^ (r & 7)) << 2);
        float4 a = *(const float4*)(b0);
        float4 b = *(const float4*)(b0 + 4096);
        float4 c = *(const float4*)(b0 + 8192);
        float4 d = *(const float4*)(b0 + 12288);
        float4 s = { -((a.x + b.x) + (c.x + d.x)),
                     -((a.y + b.y) + (c.y + d.y)),
                     -((a.z + b.z) + (c.z + d.z)),
                     -((a.w + b.w) + (c.w + d.w)) };
        *(float4*)&out[(size_t)(grow0 + r) * M_CONS + gcol0 + (qd << 2)] = s;
    }
}

// K2: in-place row softmax over M_CONS=512. One wave per row, 8 f32/lane.
__global__ __launch_bounds__(256) void softmax_kernel(float* __restrict__ out) {
    const int row  = blockIdx.x * 4 + (threadIdx.x >> 6);
    const int lane = threadIdx.x & 63;
    float* p = out + (size_t)row * M_CONS + lane * 8;

    float4 v0 = *(const float4*)p;
    float4 v1 = *(const float4*)(p + 4);

    float m = fmaxf(fmaxf(fmaxf(v0.x, v0.y), fmaxf(v0.z, v0.w)),
                    fmaxf(fmaxf(v1.x, v1.y), fmaxf(v1.z, v1.w)));
#pragma unroll
    for (int off = 32; off > 0; off >>= 1) m = fmaxf(m, __shfl_xor(m, off));

    float e[8];
    e[0] = __expf(v0.x - m); e[1] = __expf(v0.y - m);
    e[2] = __expf(v0.z - m); e[3] = __expf(v0.w - m);
    e[4] = __expf(v1.x - m); e[5] = __expf(v1.y - m);
    e[6] = __expf(v1.z - m); e[7] = __expf(v1.w - m);

    float s = ((e[0] + e[1]) + (e[2] + e[3])) + ((e[4] + e[5]) + (e[6] + e[7]));
#pragma unroll
    for (int off = 32; off > 0; off >>= 1) s += __shfl_xor(s, off);

    const float inv = 1.f / s;
    float4 o0 = { e[0] * inv, e[1] * inv, e[2] * inv, e[3] * inv };
    float4 o1 = { e[4] * inv, e[5] * inv, e[6] * inv, e[7] * inv };
    *(float4*)p       = o0;
    *(float4*)(p + 4) = o1;
}

extern "C" void kernel_launch(void* const* d_in, const int* in_sizes, int n_in,
                              void* d_out, int out_size, void* d_ws, size_t ws_size,
                              hipStream_t stream) {
    const float* sites = (const float*)d_in[0];
    const float* cons  = (const float*)d_in[1];
    float* out = (float*)d_out;

    dim3 g1(N_SITES / 64, M_CONS / 64);          // 64 x 8 = 512 blocks, 2/CU
    dist_kernel<<<g1, 256, 0, stream>>>(sites, cons, out);

    softmax_kernel<<<N_SITES / 4, 256, 0, stream>>>(out);
}